// Round 10
// baseline (483.916 us; speedup 1.0000x reference)
//
#include <hip/hip_runtime.h>
#include <math.h>

constexpr int   NGc    = 128;
constexpr int   NCELL  = NGc * NGc;
constexpr int   NBIN   = 128 * 32;          // bin = (bx, by>>2) : 4096
constexpr float DTc    = 1e-4f;
constexpr float DXc    = 1.0f / 128.0f;
constexpr float INV_DX = 128.0f;
constexpr float P_VOLc = (DXc * 0.5f) * (DXc * 0.5f);
constexpr float P_MASSc = P_VOLc * 1.0f;
constexpr float GRAV   = 9.8f;
constexpr float STRESS_COEF = -DTc * P_VOLc * 4.0f * INV_DX * INV_DX;

// ---------------------------------------------------------------------------
// S1: bin to 4096 bins (cell-row x col-group). LDS u32 hist + local rank ->
// key = bin<<20 | pos_in_bin.  (u32 LDS atomics fine; fp32 LDS atomics are
// ~0.3/cy/CU on gfx950 — never use them.)
// ---------------------------------------------------------------------------
constexpr int S1_PPT = 16;
constexpr int S1_BLK = 1024;

__global__ __launch_bounds__(1024) void bin_kernel(
    const float2* __restrict__ x, unsigned* __restrict__ key,
    unsigned* __restrict__ gcnt, int n)
{
    __shared__ unsigned hist[NBIN];
#pragma unroll
    for (int j = 0; j < NBIN / S1_BLK; j++)
        hist[threadIdx.x + j * S1_BLK] = 0;
    __syncthreads();

    int base_i = blockIdx.x * (S1_BLK * S1_PPT);
    unsigned t_arr[S1_PPT], r_arr[S1_PPT];
#pragma unroll
    for (int k = 0; k < S1_PPT; k++) {
        int i = base_i + k * S1_BLK + threadIdx.x;
        unsigned t = 0, r = 0;
        if (i < n) {
            float2 xi = x[i];
            int bx = (int)floorf(xi.x * INV_DX - 0.5f);
            int by = (int)floorf(xi.y * INV_DX - 0.5f);
            t = (unsigned)(bx * 32 + (by >> 2));
            r = atomicAdd(&hist[t], 1u);
        }
        t_arr[k] = t; r_arr[k] = r;
    }
    __syncthreads();

#pragma unroll
    for (int j = 0; j < NBIN / S1_BLK; j++) {
        int b = threadIdx.x + j * S1_BLK;
        unsigned c = hist[b];
        __syncthreads();
        hist[b] = c ? atomicAdd(&gcnt[b], c) : 0u;
        __syncthreads();
    }

#pragma unroll
    for (int k = 0; k < S1_PPT; k++) {
        int i = base_i + k * S1_BLK + threadIdx.x;
        if (i < n)
            key[i] = (t_arr[k] << 20) | (hist[t_arr[k]] + r_arr[k]);
    }
}

// ---------------------------------------------------------------------------
// S2: exclusive scan over 4096 bin counts (single block, 4/thread) + sentinel
// ---------------------------------------------------------------------------
__global__ __launch_bounds__(1024) void scan_kernel(
    const unsigned* __restrict__ gcnt, unsigned* __restrict__ binoff)
{
    __shared__ unsigned s[1024];
    int t = threadIdx.x;
    unsigned v0 = gcnt[4 * t], v1 = gcnt[4 * t + 1];
    unsigned v2 = gcnt[4 * t + 2], v3 = gcnt[4 * t + 3];
    unsigned p = v0 + v1 + v2 + v3;
    s[t] = p;
    __syncthreads();
    for (int d = 1; d < 1024; d <<= 1) {
        unsigned add = (t >= d) ? s[t - d] : 0u;
        __syncthreads();
        s[t] += add;
        __syncthreads();
    }
    unsigned base = s[t] - p;
    binoff[4 * t]     = base;
    binoff[4 * t + 1] = base + v0;
    binoff[4 * t + 2] = base + v0 + v1;
    binoff[4 * t + 3] = base + v0 + v1 + v2;
    if (t == 1023) binoff[4096] = s[1023];
}

// ---------------------------------------------------------------------------
// Stage A, 4 particles/thread: each weight fetch feeds 4 FMAs. Backward keeps
// ReLU gates as bitmasks so 4 particle streams fit in registers.
// ---------------------------------------------------------------------------
constexpr int PPT = 4;

__global__ __launch_bounds__(256, 2) void stagea_kernel(
    const float2* __restrict__ x, const float2* __restrict__ v,
    const float4* __restrict__ C, const float4* __restrict__ F,
    const float* __restrict__ W1, const float* __restrict__ b1,
    const float* __restrict__ W2, const float* __restrict__ b2,
    const float* __restrict__ W3, const float* __restrict__ b3,
    const float* __restrict__ W4,
    const unsigned* __restrict__ key, const unsigned* __restrict__ binoff,
    float4* __restrict__ recs, int n)
{
    const int tb = blockIdx.x * (256 * PPT) + threadIdx.x;

    float xix[PPT], xiy[PPT], pvx[PPT], pvy[PPT];
    float Ci0[PPT], Ci1[PPT], Ci2[PPT], Ci3[PPT];
    float Fn00[PPT], Fn01[PPT], Fn10[PPT], Fn11[PPT];
    float tr[PPT], Cm00a[PPT], Cm01a[PPT], Cm11a[PPT], delta[PPT], gate[PPT];
    float feat0[PPT], feat1[PPT];
    bool  act[PPT];

#pragma unroll
    for (int p = 0; p < PPT; p++) {
        int i = tb + 256 * p;
        act[p] = (i < n);
        float2 xi = act[p] ? x[i] : make_float2(0.f, 0.f);
        float2 vi = act[p] ? v[i] : make_float2(0.f, 0.f);
        float4 Ci = act[p] ? C[i] : make_float4(0.f, 0.f, 0.f, 0.f);
        float4 Fi = act[p] ? F[i] : make_float4(1.f, 0.f, 0.f, 1.f);

        xix[p] = xi.x; xiy[p] = xi.y;
        pvx[p] = P_MASSc * vi.x; pvy[p] = P_MASSc * vi.y;
        Ci0[p] = Ci.x; Ci1[p] = Ci.y; Ci2[p] = Ci.z; Ci3[p] = Ci.w;

        float f00 = Fi.x + DTc * (Ci.x * Fi.x + Ci.y * Fi.z);
        float f01 = Fi.y + DTc * (Ci.x * Fi.y + Ci.y * Fi.w);
        float f10 = Fi.z + DTc * (Ci.z * Fi.x + Ci.w * Fi.z);
        float f11 = Fi.w + DTc * (Ci.z * Fi.y + Ci.w * Fi.w);
        Fn00[p] = f00; Fn01[p] = f01; Fn10[p] = f10; Fn11[p] = f11;

        float c00 = f00 * f00 + f10 * f10;
        float c01 = f00 * f01 + f10 * f11;
        float c11 = f01 * f01 + f11 * f11;
        Cm00a[p] = c00; Cm01a[p] = c01; Cm11a[p] = c11;

        float trp = c00 + c11;
        float det = c00 * c11 - c01 * c01;
        float g   = trp * trp - 4.0f * det;
        gate[p]   = (g > 1e-8f) ? 1.0f : 0.0f;
        float dl  = sqrtf(fmaxf(g, 1e-8f));
        tr[p] = trp; delta[p] = dl;
        feat0[p] = 0.5f * (trp + dl);
        feat1[p] = 0.5f * (trp - dl);
    }

    // ---- layer 1 ----
    float h1[PPT][16];
#pragma unroll
    for (int j = 0; j < 16; j++) {
        float w0 = W1[2 * j], w1 = W1[2 * j + 1], bb = b1[j];
#pragma unroll
        for (int p = 0; p < PPT; p++)
            h1[p][j] = fmaxf(fmaf(w0, feat0[p], fmaf(w1, feat1[p], bb)), 0.0f);
    }

    // ---- layer 2 ----
    float h2[PPT][16];
#pragma unroll
    for (int j = 0; j < 16; j++) {
        float bb = b2[j];
#pragma unroll
        for (int p = 0; p < PPT; p++) {
            float a = bb;
#pragma unroll
            for (int kk = 0; kk < 16; kk++) a = fmaf(W2[j * 16 + kk], h1[p][kk], a);
            h2[p][j] = fmaxf(a, 0.0f);
        }
    }

    // compress h1 -> gate bitmask, release h1 registers
    unsigned g1[PPT];
#pragma unroll
    for (int p = 0; p < PPT; p++) {
        unsigned m = 0;
#pragma unroll
        for (int j = 0; j < 16; j++) m |= (h1[p][j] > 0.0f) ? (1u << j) : 0u;
        g1[p] = m;
    }

    // ---- layer 3 forward, emitting dh3 = gate3 ? W4 : 0 directly ----
    float dh3[PPT][16];
#pragma unroll
    for (int j = 0; j < 16; j++) {
        float bb = b3[j], w4 = W4[j];
#pragma unroll
        for (int p = 0; p < PPT; p++) {
            float a = bb;
#pragma unroll
            for (int kk = 0; kk < 16; kk++) a = fmaf(W3[j * 16 + kk], h2[p][kk], a);
            dh3[p][j] = (a > 0.0f) ? w4 : 0.0f;
        }
    }

    // compress h2 -> gate bitmask, release h2 registers
    unsigned g2[PPT];
#pragma unroll
    for (int p = 0; p < PPT; p++) {
        unsigned m = 0;
#pragma unroll
        for (int j = 0; j < 16; j++) m |= (h2[p][j] > 0.0f) ? (1u << j) : 0u;
        g2[p] = m;
    }

    // ---- backward through layer 3 ----
    float dh2[PPT][16];
#pragma unroll
    for (int kk = 0; kk < 16; kk++) {
#pragma unroll
        for (int p = 0; p < PPT; p++) {
            float a = 0.0f;
#pragma unroll
            for (int j = 0; j < 16; j++) a = fmaf(W3[j * 16 + kk], dh3[p][j], a);
            dh2[p][kk] = ((g2[p] >> kk) & 1u) ? a : 0.0f;
        }
    }

    // ---- backward through layer 2 + layer 1 ----
    float df0[PPT], df1[PPT];
#pragma unroll
    for (int p = 0; p < PPT; p++) { df0[p] = 0.0f; df1[p] = 0.0f; }
#pragma unroll
    for (int kk = 0; kk < 16; kk++) {
        float w0 = W1[2 * kk], w1 = W1[2 * kk + 1];
#pragma unroll
        for (int p = 0; p < PPT; p++) {
            float a = 0.0f;
#pragma unroll
            for (int j = 0; j < 16; j++) a = fmaf(W2[j * 16 + kk], dh2[p][j], a);
            a = ((g1[p] >> kk) & 1u) ? a : 0.0f;
            df0[p] = fmaf(w0, a, df0[p]);
            df1[p] = fmaf(w1, a, df1[p]);
        }
    }

    // ---- epilogue ----
#pragma unroll
    for (int p = 0; p < PPT; p++) {
        if (!act[p]) continue;
        int i = tb + 256 * p;

        float half_sum  = 0.5f * (df0[p] + df1[p]);
        float half_diff = 0.5f * (df0[p] - df1[p]);
        float inv_delta = 1.0f / delta[p];
        float dtr  = half_sum + half_diff * tr[p] * inv_delta * gate[p];
        float ddet = half_diff * (-2.0f) * inv_delta * gate[p];

        float S00 = 2.0f * (dtr + ddet * Cm11a[p]);
        float S11 = 2.0f * (dtr + ddet * Cm00a[p]);
        float S01 = -2.0f * ddet * Cm01a[p];

        float dF00 = Fn00[p] * S00 + Fn01[p] * S01;
        float dF01 = Fn00[p] * S01 + Fn01[p] * S11;
        float dF10 = Fn10[p] * S00 + Fn11[p] * S01;
        float dF11 = Fn10[p] * S01 + Fn11[p] * S11;

        float a00 = STRESS_COEF * dF00 + P_MASSc * Ci0[p];
        float a01 = STRESS_COEF * dF01 + P_MASSc * Ci1[p];
        float a10 = STRESS_COEF * dF10 + P_MASSc * Ci2[p];
        float a11 = STRESS_COEF * dF11 + P_MASSc * Ci3[p];

        unsigned k = key[i];
        unsigned pos = binoff[k >> 20] + (k & 0xFFFFFu);

        recs[2 * (size_t)pos]     = make_float4(xix[p], xiy[p], a00, a01);
        recs[2 * (size_t)pos + 1] = make_float4(a10, a11, pvx[p], pvy[p]);
    }
}

// ---------------------------------------------------------------------------
// Gather-form grid build, 8 nodes per wave, REGISTER accumulators (no LDS,
// no atomics). Each record read once serves 8 nodes -> 4x less L2 traffic.
// ---------------------------------------------------------------------------
__global__ __launch_bounds__(256) void grid_gather_kernel(
    const float4* __restrict__ recs, const unsigned* __restrict__ binoff,
    float2* __restrict__ gv)
{
    int wid  = threadIdx.x >> 6;
    int lane = threadIdx.x & 63;
    int w    = blockIdx.x * 4 + wid;            // 512 blocks * 4 waves = 2048
    int base = w * 8;                           // 8 consecutive nodes, one row
    int gi   = base >> 7;
    int gj0  = base & 127;

    float accx[8], accy[8], accm[8];
#pragma unroll
    for (int t = 0; t < 8; t++) { accx[t] = 0.f; accy[t] = 0.f; accm[t] = 0.f; }

    int c0 = max(gj0 - 2, 0) >> 2;
    int c1 = (gj0 + 7) >> 2;                    // <= 31 always

#pragma unroll
    for (int r = 0; r < 3; r++) {
        int bx = gi - 2 + r;                    // ii = gi - bx = 2 - r
        if (bx < 0 || bx > 127) continue;       // wave-uniform
        int lo = (int)binoff[bx * 32 + c0];
        int hi = (int)binoff[bx * 32 + c1 + 1];
        for (int k = lo + lane; k < hi; k += 64) {
            float4 r0 = recs[2 * (size_t)k];
            float4 r1 = recs[2 * (size_t)k + 1];

            float py = r0.y * INV_DX;
            int   by = (int)floorf(py - 0.5f);
            float fy = py - (float)by;
            float fx = r0.x * INV_DX - (float)bx;

            float wx;
            if (r == 0)      wx = 0.5f * (fx - 0.5f) * (fx - 0.5f);   // ii = 2
            else if (r == 1) wx = 0.75f - (fx - 1.0f) * (fx - 1.0f);  // ii = 1
            else             wx = 0.5f * (1.5f - fx) * (1.5f - fx);   // ii = 0

            float wy0 = 0.5f * (1.5f - fy) * (1.5f - fy);
            float wy1 = 0.75f - (fy - 1.0f) * (fy - 1.0f);
            float wy2 = 0.5f * (fy - 0.5f) * (fy - 0.5f);

            float dxp = (float)gi * DXc - r0.x;
            float mxb = r1.z + r0.z * dxp;      // + r0.w * dyp per node
            float myb = r1.w + r1.x * dxp;      // + r1.y * dyp per node

#pragma unroll
            for (int t = 0; t < 8; t++) {
                int jj = gj0 + t - by;
                bool ok = (jj >= 0) && (jj <= 2);
                float wy = (jj == 0) ? wy0 : ((jj == 1) ? wy1 : wy2);
                float wt = ok ? (wx * wy) : 0.0f;
                float dyp = (float)(gj0 + t) * DXc - r0.y;
                accx[t] = fmaf(wt, mxb + r0.w * dyp, accx[t]);
                accy[t] = fmaf(wt, myb + r1.y * dyp, accy[t]);
                accm[t] += wt * P_MASSc;
            }
        }
    }

#pragma unroll
    for (int t = 0; t < 8; t++) {
#pragma unroll
        for (int off = 32; off >= 1; off >>= 1) {
            accx[t] += __shfl_xor(accx[t], off, 64);
            accy[t] += __shfl_xor(accy[t], off, 64);
            accm[t] += __shfl_xor(accm[t], off, 64);
        }
    }

    // lane t (t<8) selects node t's sums
    float vx = 0.f, vy = 0.f, m = 0.f;
#pragma unroll
    for (int t = 0; t < 8; t++) {
        if (lane == t) { vx = accx[t]; vy = accy[t]; m = accm[t]; }
    }

    if (lane < 8) {
        int gj = gj0 + lane;
        if (m > 0.0f) {
            float inv_m = 1.0f / m;
            vx *= inv_m;
            vy *= inv_m;
        }
        vy -= DTc * GRAV;
        if (gi < 3)        vx = fmaxf(vx, 0.0f);
        if (gi >= NGc - 3) vx = fminf(vx, 0.0f);
        if (gj < 3)        vy = fmaxf(vy, 0.0f);
        if (gj >= NGc - 3) vy = fminf(vy, 0.0f);
        gv[base + lane] = make_float2(vx, vy);
    }
}

// ---------------------------------------------------------------------------
// G2P (+ Fnew recompute and write, coalesced)
// ---------------------------------------------------------------------------
__global__ __launch_bounds__(256) void g2p_kernel(
    const float2* __restrict__ x, const float2* __restrict__ v,
    const float4* __restrict__ C, const float4* __restrict__ F,
    const int* __restrict__ material, const float* __restrict__ Jp,
    const float2* __restrict__ gv,
    float2* __restrict__ out_x, float2* __restrict__ out_v,
    float4* __restrict__ out_C, float4* __restrict__ out_F,
    float* __restrict__ out_mat, float* __restrict__ out_Jp, int n)
{
    int i = blockIdx.x * 256 + threadIdx.x;
    if (i >= n) return;

    float2 xi = x[i];
    float2 vi = v[i];
    float4 Ci = C[i];
    float4 Fi = F[i];

    float Fn00 = Fi.x + DTc * (Ci.x * Fi.x + Ci.y * Fi.z);
    float Fn01 = Fi.y + DTc * (Ci.x * Fi.y + Ci.y * Fi.w);
    float Fn10 = Fi.z + DTc * (Ci.z * Fi.x + Ci.w * Fi.z);
    float Fn11 = Fi.w + DTc * (Ci.z * Fi.y + Ci.w * Fi.w);

    float px = xi.x * INV_DX, py = xi.y * INV_DX;
    int   bx = (int)floorf(px - 0.5f);
    int   by = (int)floorf(py - 0.5f);
    float fx = px - (float)bx;
    float fy = py - (float)by;
    float wxs[3] = {0.5f * (1.5f - fx) * (1.5f - fx),
                    0.75f - (fx - 1.0f) * (fx - 1.0f),
                    0.5f * (fx - 0.5f) * (fx - 0.5f)};
    float wys[3] = {0.5f * (1.5f - fy) * (1.5f - fy),
                    0.75f - (fy - 1.0f) * (fy - 1.0f),
                    0.5f * (fy - 0.5f) * (fy - 0.5f)};

    float accvx = 0.0f, accvy = 0.0f;
    float accC00 = 0.0f, accC01 = 0.0f, accC10 = 0.0f, accC11 = 0.0f;

#pragma unroll
    for (int ii = 0; ii < 3; ii++) {
        float gxx = (float)(bx + ii) * DXc;
#pragma unroll
        for (int jj = 0; jj < 3; jj++) {
            float wt = wxs[ii] * wys[jj];
            float2 gvn = gv[(bx + ii) * NGc + (by + jj)];
            float gxy = (float)(by + jj) * DXc;
            accvx  += wt * gvn.x;
            accvy  += wt * gvn.y;
            accC00 += wt * gvn.x * gxx;
            accC01 += wt * gvn.x * gxy;
            accC10 += wt * gvn.y * gxx;
            accC11 += wt * gvn.y * gxy;
        }
    }

    const float k4 = 4.0f * INV_DX * INV_DX;
    out_x[i]   = make_float2(xi.x + DTc * vi.x, xi.y + DTc * vi.y);
    out_v[i]   = make_float2(accvx, accvy);
    out_C[i]   = make_float4(k4 * (accC00 - accvx * xi.x),
                             k4 * (accC01 - accvx * xi.y),
                             k4 * (accC10 - accvy * xi.x),
                             k4 * (accC11 - accvy * xi.y));
    out_F[i]   = make_float4(Fn00, Fn01, Fn10, Fn11);
    out_mat[i] = (float)material[i];
    out_Jp[i]  = Jp[i];
}

// ---------------------------------------------------------------------------
extern "C" void kernel_launch(void* const* d_in, const int* in_sizes, int n_in,
                              void* d_out, int out_size, void* d_ws, size_t ws_size,
                              hipStream_t stream)
{
    const float2* x  = (const float2*)d_in[0];
    const float2* v  = (const float2*)d_in[1];
    const float4* C  = (const float4*)d_in[2];
    const float4* F  = (const float4*)d_in[3];
    const int* material = (const int*)d_in[4];
    const float* Jp  = (const float*)d_in[5];
    const float* W1  = (const float*)d_in[8];
    const float* b1  = (const float*)d_in[9];
    const float* W2  = (const float*)d_in[10];
    const float* b2  = (const float*)d_in[11];
    const float* W3  = (const float*)d_in[12];
    const float* b3  = (const float*)d_in[13];
    const float* W4  = (const float*)d_in[14];

    const int n = in_sizes[0] / 2;

    // d_ws: gcnt (NBIN u32) + binoff (NBIN+1 u32) + gv (NCELL float2)
    unsigned* gcnt   = (unsigned*)d_ws;
    unsigned* binoff = gcnt + NBIN;
    float2*   gv     = (float2*)(binoff + NBIN + 1);

    float* out = (float*)d_out;
    float2* out_x   = (float2*)out;                    // 0..2N
    float2* out_v   = (float2*)(out + 2 * (size_t)n);  // 2N..4N
    float4* out_C   = (float4*)(out + 4 * (size_t)n);  // 4N..8N
    float4* out_F   = (float4*)(out + 8 * (size_t)n);  // 8N..12N
    float*  out_mat = out + 12 * (size_t)n;            // 12N..13N
    float*  out_Jp  = out + 13 * (size_t)n;            // 13N..14N

    // middle-phase scratch inside d_out (consumed before g2p overwrites):
    float4*   recs = (float4*)(out + 2 * (size_t)n);   // 8N floats: 2N..10N
    unsigned* key  = (unsigned*)out_mat;               // N u32:     12N..13N

    hipMemsetAsync(gcnt, 0, NBIN * sizeof(unsigned), stream);

    int s1_blocks = (n + S1_BLK * S1_PPT - 1) / (S1_BLK * S1_PPT);
    int sa_blocks = (n + 256 * PPT - 1) / (256 * PPT);
    int blocks    = (n + 255) / 256;
    bin_kernel<<<s1_blocks, S1_BLK, 0, stream>>>(x, key, gcnt, n);
    scan_kernel<<<1, 1024, 0, stream>>>(gcnt, binoff);
    stagea_kernel<<<sa_blocks, 256, 0, stream>>>(x, v, C, F, W1, b1, W2, b2, W3, b3, W4,
                                                 key, binoff, recs, n);
    grid_gather_kernel<<<NCELL / 8 / 4, 256, 0, stream>>>(recs, binoff, gv);
    g2p_kernel<<<blocks, 256, 0, stream>>>(x, v, C, F, material, Jp, gv,
                                           out_x, out_v, out_C, out_F, out_mat, out_Jp, n);
}

// Round 11
// 387.132 us; speedup vs baseline: 1.2500x; 1.2500x over previous
//
#include <hip/hip_runtime.h>
#include <math.h>

constexpr int   NGc    = 128;
constexpr int   NCELL  = NGc * NGc;
constexpr int   NBIN   = 128 * 32;          // bin = (bx, by>>2) : 4096
constexpr float DTc    = 1e-4f;
constexpr float DXc    = 1.0f / 128.0f;
constexpr float INV_DX = 128.0f;
constexpr float P_VOLc = (DXc * 0.5f) * (DXc * 0.5f);
constexpr float P_MASSc = P_VOLc * 1.0f;
constexpr float GRAV   = 9.8f;
constexpr float STRESS_COEF = -DTc * P_VOLc * 4.0f * INV_DX * INV_DX;

// 16-term dot: row (4x float4) . H[16], fully fmaf-chained
#define DOT16(W0_, W1_, W2_, W3_, H) \
  fmaf((W3_).w,(H)[15],fmaf((W3_).z,(H)[14],fmaf((W3_).y,(H)[13],fmaf((W3_).x,(H)[12], \
  fmaf((W2_).w,(H)[11],fmaf((W2_).z,(H)[10],fmaf((W2_).y,(H)[9], fmaf((W2_).x,(H)[8],  \
  fmaf((W1_).w,(H)[7], fmaf((W1_).z,(H)[6], fmaf((W1_).y,(H)[5], fmaf((W1_).x,(H)[4],  \
  fmaf((W0_).w,(H)[3], fmaf((W0_).z,(H)[2], fmaf((W0_).y,(H)[1], fmaf((W0_).x,(H)[0], 0.0f))))))))))))))))

// ACC[0..15] += row * s
#define AXPY16(W0_, W1_, W2_, W3_, S_, ACC) do {            \
  (ACC)[0]  = fmaf((W0_).x,(S_),(ACC)[0]);                  \
  (ACC)[1]  = fmaf((W0_).y,(S_),(ACC)[1]);                  \
  (ACC)[2]  = fmaf((W0_).z,(S_),(ACC)[2]);                  \
  (ACC)[3]  = fmaf((W0_).w,(S_),(ACC)[3]);                  \
  (ACC)[4]  = fmaf((W1_).x,(S_),(ACC)[4]);                  \
  (ACC)[5]  = fmaf((W1_).y,(S_),(ACC)[5]);                  \
  (ACC)[6]  = fmaf((W1_).z,(S_),(ACC)[6]);                  \
  (ACC)[7]  = fmaf((W1_).w,(S_),(ACC)[7]);                  \
  (ACC)[8]  = fmaf((W2_).x,(S_),(ACC)[8]);                  \
  (ACC)[9]  = fmaf((W2_).y,(S_),(ACC)[9]);                  \
  (ACC)[10] = fmaf((W2_).z,(S_),(ACC)[10]);                 \
  (ACC)[11] = fmaf((W2_).w,(S_),(ACC)[11]);                 \
  (ACC)[12] = fmaf((W3_).x,(S_),(ACC)[12]);                 \
  (ACC)[13] = fmaf((W3_).y,(S_),(ACC)[13]);                 \
  (ACC)[14] = fmaf((W3_).z,(S_),(ACC)[14]);                 \
  (ACC)[15] = fmaf((W3_).w,(S_),(ACC)[15]);                 \
} while (0)

// ---------------------------------------------------------------------------
// S1: bin to 4096 bins (cell-row x col-group). LDS u32 hist + local rank ->
// key = bin<<20 | pos_in_bin.  (u32 LDS atomics fine; fp32 LDS atomics are
// ~0.3/cy/CU on gfx950 — never use them.)
// ---------------------------------------------------------------------------
constexpr int S1_PPT = 16;
constexpr int S1_BLK = 1024;

__global__ __launch_bounds__(1024) void bin_kernel(
    const float2* __restrict__ x, unsigned* __restrict__ key,
    unsigned* __restrict__ gcnt, int n)
{
    __shared__ unsigned hist[NBIN];
#pragma unroll
    for (int j = 0; j < NBIN / S1_BLK; j++)
        hist[threadIdx.x + j * S1_BLK] = 0;
    __syncthreads();

    int base_i = blockIdx.x * (S1_BLK * S1_PPT);
    unsigned t_arr[S1_PPT], r_arr[S1_PPT];
#pragma unroll
    for (int k = 0; k < S1_PPT; k++) {
        int i = base_i + k * S1_BLK + threadIdx.x;
        unsigned t = 0, r = 0;
        if (i < n) {
            float2 xi = x[i];
            int bx = (int)floorf(xi.x * INV_DX - 0.5f);
            int by = (int)floorf(xi.y * INV_DX - 0.5f);
            t = (unsigned)(bx * 32 + (by >> 2));
            r = atomicAdd(&hist[t], 1u);
        }
        t_arr[k] = t; r_arr[k] = r;
    }
    __syncthreads();

#pragma unroll
    for (int j = 0; j < NBIN / S1_BLK; j++) {
        int b = threadIdx.x + j * S1_BLK;
        unsigned c = hist[b];
        __syncthreads();
        hist[b] = c ? atomicAdd(&gcnt[b], c) : 0u;
        __syncthreads();
    }

#pragma unroll
    for (int k = 0; k < S1_PPT; k++) {
        int i = base_i + k * S1_BLK + threadIdx.x;
        if (i < n)
            key[i] = (t_arr[k] << 20) | (hist[t_arr[k]] + r_arr[k]);
    }
}

// ---------------------------------------------------------------------------
// S2: exclusive scan over 4096 bin counts (single block, 4/thread) + sentinel
// ---------------------------------------------------------------------------
__global__ __launch_bounds__(1024) void scan_kernel(
    const unsigned* __restrict__ gcnt, unsigned* __restrict__ binoff)
{
    __shared__ unsigned s[1024];
    int t = threadIdx.x;
    unsigned v0 = gcnt[4 * t], v1 = gcnt[4 * t + 1];
    unsigned v2 = gcnt[4 * t + 2], v3 = gcnt[4 * t + 3];
    unsigned p = v0 + v1 + v2 + v3;
    s[t] = p;
    __syncthreads();
    for (int d = 1; d < 1024; d <<= 1) {
        unsigned add = (t >= d) ? s[t - d] : 0u;
        __syncthreads();
        s[t] += add;
        __syncthreads();
    }
    unsigned base = s[t] - p;
    binoff[4 * t]     = base;
    binoff[4 * t + 1] = base + v0;
    binoff[4 * t + 2] = base + v0 + v1;
    binoff[4 * t + 3] = base + v0 + v1 + v2;
    if (t == 1023) binoff[4096] = s[1023];
}

// ---------------------------------------------------------------------------
// Stage A, 2 particles/thread (A/B streams in separate [16] arrays so SROA
// keeps everything in registers). All weight matrices read row-major as
// float4; backward passes are j-outer AXPY so loads stay row-contiguous.
// ---------------------------------------------------------------------------
__global__ __launch_bounds__(256, 2) void stagea_kernel(
    const float2* __restrict__ x, const float2* __restrict__ v,
    const float4* __restrict__ C, const float4* __restrict__ F,
    const float* __restrict__ W1, const float* __restrict__ b1,
    const float* __restrict__ W2, const float* __restrict__ b2,
    const float* __restrict__ W3, const float* __restrict__ b3,
    const float* __restrict__ W4,
    const unsigned* __restrict__ key, const unsigned* __restrict__ binoff,
    float4* __restrict__ recs, int n)
{
    const float2* W1v = (const float2*)W1;
    const float4* W2v = (const float4*)W2;
    const float4* W3v = (const float4*)W3;

    const int i0 = blockIdx.x * 512 + threadIdx.x;
    const int i1 = i0 + 256;
    const bool a0 = (i0 < n), a1 = (i1 < n);

    float2 xiA = a0 ? x[i0] : make_float2(0.f, 0.f);
    float2 viA = a0 ? v[i0] : make_float2(0.f, 0.f);
    float4 CiA = a0 ? C[i0] : make_float4(0.f, 0.f, 0.f, 0.f);
    float4 FiA = a0 ? F[i0] : make_float4(1.f, 0.f, 0.f, 1.f);
    float2 xiB = a1 ? x[i1] : make_float2(0.f, 0.f);
    float2 viB = a1 ? v[i1] : make_float2(0.f, 0.f);
    float4 CiB = a1 ? C[i1] : make_float4(0.f, 0.f, 0.f, 0.f);
    float4 FiB = a1 ? F[i1] : make_float4(1.f, 0.f, 0.f, 1.f);

    // geometry A
    float FnA00 = FiA.x + DTc * (CiA.x * FiA.x + CiA.y * FiA.z);
    float FnA01 = FiA.y + DTc * (CiA.x * FiA.y + CiA.y * FiA.w);
    float FnA10 = FiA.z + DTc * (CiA.z * FiA.x + CiA.w * FiA.z);
    float FnA11 = FiA.w + DTc * (CiA.z * FiA.y + CiA.w * FiA.w);
    float CmA00 = FnA00 * FnA00 + FnA10 * FnA10;
    float CmA01 = FnA00 * FnA01 + FnA10 * FnA11;
    float CmA11 = FnA01 * FnA01 + FnA11 * FnA11;
    float trA   = CmA00 + CmA11;
    float detA  = CmA00 * CmA11 - CmA01 * CmA01;
    float gA_   = trA * trA - 4.0f * detA;
    float gateA = (gA_ > 1e-8f) ? 1.0f : 0.0f;
    float deltaA = sqrtf(fmaxf(gA_, 1e-8f));
    float feat0A = 0.5f * (trA + deltaA);
    float feat1A = 0.5f * (trA - deltaA);

    // geometry B
    float FnB00 = FiB.x + DTc * (CiB.x * FiB.x + CiB.y * FiB.z);
    float FnB01 = FiB.y + DTc * (CiB.x * FiB.y + CiB.y * FiB.w);
    float FnB10 = FiB.z + DTc * (CiB.z * FiB.x + CiB.w * FiB.z);
    float FnB11 = FiB.w + DTc * (CiB.z * FiB.y + CiB.w * FiB.w);
    float CmB00 = FnB00 * FnB00 + FnB10 * FnB10;
    float CmB01 = FnB00 * FnB01 + FnB10 * FnB11;
    float CmB11 = FnB01 * FnB01 + FnB11 * FnB11;
    float trB   = CmB00 + CmB11;
    float detB  = CmB00 * CmB11 - CmB01 * CmB01;
    float gB_   = trB * trB - 4.0f * detB;
    float gateB = (gB_ > 1e-8f) ? 1.0f : 0.0f;
    float deltaB = sqrtf(fmaxf(gB_, 1e-8f));
    float feat0B = 0.5f * (trB + deltaB);
    float feat1B = 0.5f * (trB - deltaB);

    // ---- layer 1 ----
    float h1A[16], h1B[16];
#pragma unroll
    for (int j = 0; j < 16; j++) {
        float2 w = W1v[j];
        float bb = b1[j];
        h1A[j] = fmaxf(fmaf(w.x, feat0A, fmaf(w.y, feat1A, bb)), 0.0f);
        h1B[j] = fmaxf(fmaf(w.x, feat0B, fmaf(w.y, feat1B, bb)), 0.0f);
    }

    // ---- layer 2 ----
    float h2A[16], h2B[16];
#pragma unroll
    for (int j = 0; j < 16; j++) {
        float4 w0 = W2v[4 * j], w1 = W2v[4 * j + 1], w2 = W2v[4 * j + 2], w3 = W2v[4 * j + 3];
        float bb = b2[j];
        h2A[j] = fmaxf(bb + DOT16(w0, w1, w2, w3, h1A), 0.0f);
        h2B[j] = fmaxf(bb + DOT16(w0, w1, w2, w3, h1B), 0.0f);
    }

    // compress h1 -> gate masks (release h1)
    unsigned g1A = 0, g1B = 0;
#pragma unroll
    for (int j = 0; j < 16; j++) {
        g1A |= (h1A[j] > 0.0f) ? (1u << j) : 0u;
        g1B |= (h1B[j] > 0.0f) ? (1u << j) : 0u;
    }

    // ---- layer 3 forward -> dh3 = (h3>0) ? W4 : 0 directly ----
    float dh3A[16], dh3B[16];
#pragma unroll
    for (int j = 0; j < 16; j++) {
        float4 w0 = W3v[4 * j], w1 = W3v[4 * j + 1], w2 = W3v[4 * j + 2], w3 = W3v[4 * j + 3];
        float bb = b3[j], w4 = W4[j];
        float sA = bb + DOT16(w0, w1, w2, w3, h2A);
        float sB = bb + DOT16(w0, w1, w2, w3, h2B);
        dh3A[j] = (sA > 0.0f) ? w4 : 0.0f;
        dh3B[j] = (sB > 0.0f) ? w4 : 0.0f;
    }

    // compress h2 -> gate masks (release h2)
    unsigned g2A = 0, g2B = 0;
#pragma unroll
    for (int j = 0; j < 16; j++) {
        g2A |= (h2A[j] > 0.0f) ? (1u << j) : 0u;
        g2B |= (h2B[j] > 0.0f) ? (1u << j) : 0u;
    }

    // ---- backward through layer 3: dh2[k] = gate2 * sum_j W3[j][k]*dh3[j] ----
    float dh2A[16], dh2B[16];
#pragma unroll
    for (int k = 0; k < 16; k++) { dh2A[k] = 0.0f; dh2B[k] = 0.0f; }
#pragma unroll
    for (int j = 0; j < 16; j++) {
        float4 w0 = W3v[4 * j], w1 = W3v[4 * j + 1], w2 = W3v[4 * j + 2], w3 = W3v[4 * j + 3];
        float dA = dh3A[j], dB = dh3B[j];
        AXPY16(w0, w1, w2, w3, dA, dh2A);
        AXPY16(w0, w1, w2, w3, dB, dh2B);
    }
#pragma unroll
    for (int k = 0; k < 16; k++) {
        dh2A[k] = ((g2A >> k) & 1u) ? dh2A[k] : 0.0f;
        dh2B[k] = ((g2B >> k) & 1u) ? dh2B[k] : 0.0f;
    }

    // ---- backward through layer 2: dh1[k] = gate1 * sum_j W2[j][k]*dh2[j] ----
    float dh1A[16], dh1B[16];
#pragma unroll
    for (int k = 0; k < 16; k++) { dh1A[k] = 0.0f; dh1B[k] = 0.0f; }
#pragma unroll
    for (int j = 0; j < 16; j++) {
        float4 w0 = W2v[4 * j], w1 = W2v[4 * j + 1], w2 = W2v[4 * j + 2], w3 = W2v[4 * j + 3];
        float dA = dh2A[j], dB = dh2B[j];
        AXPY16(w0, w1, w2, w3, dA, dh1A);
        AXPY16(w0, w1, w2, w3, dB, dh1B);
    }

    // ---- backward through layer 1 ----
    float df0A = 0.0f, df1A = 0.0f, df0B = 0.0f, df1B = 0.0f;
#pragma unroll
    for (int k = 0; k < 16; k++) {
        float2 w = W1v[k];
        float dA = ((g1A >> k) & 1u) ? dh1A[k] : 0.0f;
        float dB = ((g1B >> k) & 1u) ? dh1B[k] : 0.0f;
        df0A = fmaf(w.x, dA, df0A);
        df1A = fmaf(w.y, dA, df1A);
        df0B = fmaf(w.x, dB, df0B);
        df1B = fmaf(w.y, dB, df1B);
    }

    // ---- epilogue A ----
    if (a0) {
        float half_sum  = 0.5f * (df0A + df1A);
        float half_diff = 0.5f * (df0A - df1A);
        float inv_delta = 1.0f / deltaA;
        float dtr  = half_sum + half_diff * trA * inv_delta * gateA;
        float ddet = half_diff * (-2.0f) * inv_delta * gateA;
        float S00 = 2.0f * (dtr + ddet * CmA11);
        float S11 = 2.0f * (dtr + ddet * CmA00);
        float S01 = -2.0f * ddet * CmA01;
        float dF00 = FnA00 * S00 + FnA01 * S01;
        float dF01 = FnA00 * S01 + FnA01 * S11;
        float dF10 = FnA10 * S00 + FnA11 * S01;
        float dF11 = FnA10 * S01 + FnA11 * S11;
        float a00 = STRESS_COEF * dF00 + P_MASSc * CiA.x;
        float a01 = STRESS_COEF * dF01 + P_MASSc * CiA.y;
        float a10 = STRESS_COEF * dF10 + P_MASSc * CiA.z;
        float a11 = STRESS_COEF * dF11 + P_MASSc * CiA.w;
        unsigned k = key[i0];
        unsigned pos = binoff[k >> 20] + (k & 0xFFFFFu);
        recs[2 * (size_t)pos]     = make_float4(xiA.x, xiA.y, a00, a01);
        recs[2 * (size_t)pos + 1] = make_float4(a10, a11, P_MASSc * viA.x, P_MASSc * viA.y);
    }
    // ---- epilogue B ----
    if (a1) {
        float half_sum  = 0.5f * (df0B + df1B);
        float half_diff = 0.5f * (df0B - df1B);
        float inv_delta = 1.0f / deltaB;
        float dtr  = half_sum + half_diff * trB * inv_delta * gateB;
        float ddet = half_diff * (-2.0f) * inv_delta * gateB;
        float S00 = 2.0f * (dtr + ddet * CmB11);
        float S11 = 2.0f * (dtr + ddet * CmB00);
        float S01 = -2.0f * ddet * CmB01;
        float dF00 = FnB00 * S00 + FnB01 * S01;
        float dF01 = FnB00 * S01 + FnB01 * S11;
        float dF10 = FnB10 * S00 + FnB11 * S01;
        float dF11 = FnB10 * S01 + FnB11 * S11;
        float a00 = STRESS_COEF * dF00 + P_MASSc * CiB.x;
        float a01 = STRESS_COEF * dF01 + P_MASSc * CiB.y;
        float a10 = STRESS_COEF * dF10 + P_MASSc * CiB.z;
        float a11 = STRESS_COEF * dF11 + P_MASSc * CiB.w;
        unsigned k = key[i1];
        unsigned pos = binoff[k >> 20] + (k & 0xFFFFFu);
        recs[2 * (size_t)pos]     = make_float4(xiB.x, xiB.y, a00, a01);
        recs[2 * (size_t)pos + 1] = make_float4(a10, a11, P_MASSc * viB.x, P_MASSc * viB.y);
    }
}

// ---------------------------------------------------------------------------
// Gather-form grid build, 8 nodes per wave, REGISTER accumulators (no LDS,
// no atomics). Each record read once serves 8 nodes.
// ---------------------------------------------------------------------------
__global__ __launch_bounds__(256) void grid_gather_kernel(
    const float4* __restrict__ recs, const unsigned* __restrict__ binoff,
    float2* __restrict__ gv)
{
    int wid  = threadIdx.x >> 6;
    int lane = threadIdx.x & 63;
    int w    = blockIdx.x * 4 + wid;
    int base = w * 8;
    int gi   = base >> 7;
    int gj0  = base & 127;

    float accx[8], accy[8], accm[8];
#pragma unroll
    for (int t = 0; t < 8; t++) { accx[t] = 0.f; accy[t] = 0.f; accm[t] = 0.f; }

    int c0 = max(gj0 - 2, 0) >> 2;
    int c1 = (gj0 + 7) >> 2;

#pragma unroll
    for (int r = 0; r < 3; r++) {
        int bx = gi - 2 + r;
        if (bx < 0 || bx > 127) continue;
        int lo = (int)binoff[bx * 32 + c0];
        int hi = (int)binoff[bx * 32 + c1 + 1];
        for (int k = lo + lane; k < hi; k += 64) {
            float4 r0 = recs[2 * (size_t)k];
            float4 r1 = recs[2 * (size_t)k + 1];

            float py = r0.y * INV_DX;
            int   by = (int)floorf(py - 0.5f);
            float fy = py - (float)by;
            float fx = r0.x * INV_DX - (float)bx;

            float wx;
            if (r == 0)      wx = 0.5f * (fx - 0.5f) * (fx - 0.5f);
            else if (r == 1) wx = 0.75f - (fx - 1.0f) * (fx - 1.0f);
            else             wx = 0.5f * (1.5f - fx) * (1.5f - fx);

            float wy0 = 0.5f * (1.5f - fy) * (1.5f - fy);
            float wy1 = 0.75f - (fy - 1.0f) * (fy - 1.0f);
            float wy2 = 0.5f * (fy - 0.5f) * (fy - 0.5f);

            float dxp = (float)gi * DXc - r0.x;
            float mxb = r1.z + r0.z * dxp;
            float myb = r1.w + r1.x * dxp;

#pragma unroll
            for (int t = 0; t < 8; t++) {
                int jj = gj0 + t - by;
                bool ok = (jj >= 0) && (jj <= 2);
                float wy = (jj == 0) ? wy0 : ((jj == 1) ? wy1 : wy2);
                float wt = ok ? (wx * wy) : 0.0f;
                float dyp = (float)(gj0 + t) * DXc - r0.y;
                accx[t] = fmaf(wt, mxb + r0.w * dyp, accx[t]);
                accy[t] = fmaf(wt, myb + r1.y * dyp, accy[t]);
                accm[t] += wt * P_MASSc;
            }
        }
    }

#pragma unroll
    for (int t = 0; t < 8; t++) {
#pragma unroll
        for (int off = 32; off >= 1; off >>= 1) {
            accx[t] += __shfl_xor(accx[t], off, 64);
            accy[t] += __shfl_xor(accy[t], off, 64);
            accm[t] += __shfl_xor(accm[t], off, 64);
        }
    }

    float vx = 0.f, vy = 0.f, m = 0.f;
#pragma unroll
    for (int t = 0; t < 8; t++) {
        if (lane == t) { vx = accx[t]; vy = accy[t]; m = accm[t]; }
    }

    if (lane < 8) {
        int gj = gj0 + lane;
        if (m > 0.0f) {
            float inv_m = 1.0f / m;
            vx *= inv_m;
            vy *= inv_m;
        }
        vy -= DTc * GRAV;
        if (gi < 3)        vx = fmaxf(vx, 0.0f);
        if (gi >= NGc - 3) vx = fminf(vx, 0.0f);
        if (gj < 3)        vy = fmaxf(vy, 0.0f);
        if (gj >= NGc - 3) vy = fminf(vy, 0.0f);
        gv[base + lane] = make_float2(vx, vy);
    }
}

// ---------------------------------------------------------------------------
// G2P (+ Fnew recompute and write, coalesced)
// ---------------------------------------------------------------------------
__global__ __launch_bounds__(256) void g2p_kernel(
    const float2* __restrict__ x, const float2* __restrict__ v,
    const float4* __restrict__ C, const float4* __restrict__ F,
    const int* __restrict__ material, const float* __restrict__ Jp,
    const float2* __restrict__ gv,
    float2* __restrict__ out_x, float2* __restrict__ out_v,
    float4* __restrict__ out_C, float4* __restrict__ out_F,
    float* __restrict__ out_mat, float* __restrict__ out_Jp, int n)
{
    int i = blockIdx.x * 256 + threadIdx.x;
    if (i >= n) return;

    float2 xi = x[i];
    float2 vi = v[i];
    float4 Ci = C[i];
    float4 Fi = F[i];

    float Fn00 = Fi.x + DTc * (Ci.x * Fi.x + Ci.y * Fi.z);
    float Fn01 = Fi.y + DTc * (Ci.x * Fi.y + Ci.y * Fi.w);
    float Fn10 = Fi.z + DTc * (Ci.z * Fi.x + Ci.w * Fi.z);
    float Fn11 = Fi.w + DTc * (Ci.z * Fi.y + Ci.w * Fi.w);

    float px = xi.x * INV_DX, py = xi.y * INV_DX;
    int   bx = (int)floorf(px - 0.5f);
    int   by = (int)floorf(py - 0.5f);
    float fx = px - (float)bx;
    float fy = py - (float)by;
    float wxs[3] = {0.5f * (1.5f - fx) * (1.5f - fx),
                    0.75f - (fx - 1.0f) * (fx - 1.0f),
                    0.5f * (fx - 0.5f) * (fx - 0.5f)};
    float wys[3] = {0.5f * (1.5f - fy) * (1.5f - fy),
                    0.75f - (fy - 1.0f) * (fy - 1.0f),
                    0.5f * (fy - 0.5f) * (fy - 0.5f)};

    float accvx = 0.0f, accvy = 0.0f;
    float accC00 = 0.0f, accC01 = 0.0f, accC10 = 0.0f, accC11 = 0.0f;

#pragma unroll
    for (int ii = 0; ii < 3; ii++) {
        float gxx = (float)(bx + ii) * DXc;
#pragma unroll
        for (int jj = 0; jj < 3; jj++) {
            float wt = wxs[ii] * wys[jj];
            float2 gvn = gv[(bx + ii) * NGc + (by + jj)];
            float gxy = (float)(by + jj) * DXc;
            accvx  += wt * gvn.x;
            accvy  += wt * gvn.y;
            accC00 += wt * gvn.x * gxx;
            accC01 += wt * gvn.x * gxy;
            accC10 += wt * gvn.y * gxx;
            accC11 += wt * gvn.y * gxy;
        }
    }

    const float k4 = 4.0f * INV_DX * INV_DX;
    out_x[i]   = make_float2(xi.x + DTc * vi.x, xi.y + DTc * vi.y);
    out_v[i]   = make_float2(accvx, accvy);
    out_C[i]   = make_float4(k4 * (accC00 - accvx * xi.x),
                             k4 * (accC01 - accvx * xi.y),
                             k4 * (accC10 - accvy * xi.x),
                             k4 * (accC11 - accvy * xi.y));
    out_F[i]   = make_float4(Fn00, Fn01, Fn10, Fn11);
    out_mat[i] = (float)material[i];
    out_Jp[i]  = Jp[i];
}

// ---------------------------------------------------------------------------
extern "C" void kernel_launch(void* const* d_in, const int* in_sizes, int n_in,
                              void* d_out, int out_size, void* d_ws, size_t ws_size,
                              hipStream_t stream)
{
    const float2* x  = (const float2*)d_in[0];
    const float2* v  = (const float2*)d_in[1];
    const float4* C  = (const float4*)d_in[2];
    const float4* F  = (const float4*)d_in[3];
    const int* material = (const int*)d_in[4];
    const float* Jp  = (const float*)d_in[5];
    const float* W1  = (const float*)d_in[8];
    const float* b1  = (const float*)d_in[9];
    const float* W2  = (const float*)d_in[10];
    const float* b2  = (const float*)d_in[11];
    const float* W3  = (const float*)d_in[12];
    const float* b3  = (const float*)d_in[13];
    const float* W4  = (const float*)d_in[14];

    const int n = in_sizes[0] / 2;

    // d_ws: gcnt (NBIN u32) + binoff (NBIN+1 u32) + gv (NCELL float2)
    unsigned* gcnt   = (unsigned*)d_ws;
    unsigned* binoff = gcnt + NBIN;
    float2*   gv     = (float2*)(binoff + NBIN + 1);

    float* out = (float*)d_out;
    float2* out_x   = (float2*)out;                    // 0..2N
    float2* out_v   = (float2*)(out + 2 * (size_t)n);  // 2N..4N
    float4* out_C   = (float4*)(out + 4 * (size_t)n);  // 4N..8N
    float4* out_F   = (float4*)(out + 8 * (size_t)n);  // 8N..12N
    float*  out_mat = out + 12 * (size_t)n;            // 12N..13N
    float*  out_Jp  = out + 13 * (size_t)n;            // 13N..14N

    // middle-phase scratch inside d_out (consumed before g2p overwrites):
    float4*   recs = (float4*)(out + 2 * (size_t)n);   // 8N floats: 2N..10N
    unsigned* key  = (unsigned*)out_mat;               // N u32:     12N..13N

    hipMemsetAsync(gcnt, 0, NBIN * sizeof(unsigned), stream);

    int s1_blocks = (n + S1_BLK * S1_PPT - 1) / (S1_BLK * S1_PPT);
    int sa_blocks = (n + 511) / 512;
    int blocks    = (n + 255) / 256;
    bin_kernel<<<s1_blocks, S1_BLK, 0, stream>>>(x, key, gcnt, n);
    scan_kernel<<<1, 1024, 0, stream>>>(gcnt, binoff);
    stagea_kernel<<<sa_blocks, 256, 0, stream>>>(x, v, C, F, W1, b1, W2, b2, W3, b3, W4,
                                                 key, binoff, recs, n);
    grid_gather_kernel<<<NCELL / 8 / 4, 256, 0, stream>>>(recs, binoff, gv);
    g2p_kernel<<<blocks, 256, 0, stream>>>(x, v, C, F, material, Jp, gv,
                                           out_x, out_v, out_C, out_F, out_mat, out_Jp, n);
}